// Round 10
// baseline (715.110 us; speedup 1.0000x reference)
//
#include <hip/hip_runtime.h>
#include <math.h>

// Problem constants
#define BATCH 16
#define CH    256
#define CRR   16      // reduced channels
#define HWSZ  16384   // 128*128
#define NPLANES (BATCH * CH)   // 4096
#define NBLK  512
#define ITER  (NPLANES / NBLK) // 8

// native vector type (ext_vector) — accepted by __builtin_nontemporal_*
typedef float vfloat4 __attribute__((ext_vector_type(4)));

// ---------------------------------------------------------------------------
// Init: zero the per-batch arrival counters (ws is poisoned 0xAA each call).
// ---------------------------------------------------------------------------
__global__ void init_kernel(unsigned int* __restrict__ cnt) {
    if (threadIdx.x < BATCH) cnt[threadIdx.x] = 0u;
}

// ---------------------------------------------------------------------------
// Persistent fused SE kernel. 512 blocks x 256 threads.
// Co-residency guaranteed: __launch_bounds__(256,2) => >=2 blocks/CU capacity,
// 2*256 = 512 >= grid, so all blocks resident; spin-waits are safe.
//
// Block p, iteration i (0..7):
//   pool plane  i*512+p   (read 64 KiB from HBM, allocating -> stays in L2)
//   arrive on cnt[batch]  (device-scope atomicAdd, release fence via atomics)
//   scale plane (i-1)*512+p  -- the plane THIS block pooled last iteration:
//       wait cnt[batch]==256, stage pooled row, fc1+leaky+fc2+sigmoid,
//       re-read plane (same CU -> same XCD L2, ~2-4 MiB window -> L2/L3 hit),
//       non-temporal store to out (no cache pollution).
// ---------------------------------------------------------------------------
__global__ __launch_bounds__(256, 2)
void se_persistent(const float* __restrict__ x,
                   const float* __restrict__ w1,   // [CRR][CH]
                   const float* __restrict__ b1,   // [CRR]
                   const float* __restrict__ w2,   // [CH][CRR]
                   const float* __restrict__ b2,   // [CH]
                   float* __restrict__ out,
                   float* pooled,                  // ws: [NPLANES]
                   unsigned int* cnt) {            // ws: [BATCH]
    const int p = blockIdx.x;     // 0..511
    const int t = threadIdx.x;    // 0..255

    __shared__ float part[4];
    __shared__ float p_lds[CH];
    __shared__ float h_lds[CRR];
    __shared__ float s_gate;

    int prev_plane = -1;

    for (int i = 0; i <= ITER; ++i) {
        // ---------------- pool phase: plane = i*NBLK + p ----------------
        if (i < ITER) {
            const int plane = i * NBLK + p;
            const int b     = plane >> 8;
            const vfloat4* pl = reinterpret_cast<const vfloat4*>(x + (size_t)plane * HWSZ);
            float sum = 0.0f;
#pragma unroll
            for (int k = 0; k < 16; ++k) {
                vfloat4 v = pl[k * 256 + t];
                sum += (v.x + v.y) + (v.z + v.w);
            }
#pragma unroll
            for (int off = 32; off > 0; off >>= 1)
                sum += __shfl_down(sum, off, 64);
            if ((t & 63) == 0) part[t >> 6] = sum;
            __syncthreads();
            if (t == 0) {
                float tot = (part[0] + part[1]) + (part[2] + part[3]);
                __hip_atomic_store(&pooled[plane], tot * (1.0f / 16384.0f),
                                   __ATOMIC_RELEASE, __HIP_MEMORY_SCOPE_AGENT);
                atomicAdd(&cnt[b], 1u);   // device-scope by default
            }
            __syncthreads();
        }

        // ---------------- scale phase: prev_plane ----------------
        if (prev_plane >= 0) {
            const int plane = prev_plane;
            const int b     = plane >> 8;
            const int c     = plane & 255;

            if (t == 0) {
                while (__hip_atomic_load(&cnt[b], __ATOMIC_ACQUIRE,
                                         __HIP_MEMORY_SCOPE_AGENT) < (unsigned)CH) {
                    __builtin_amdgcn_s_sleep(2);
                }
            }
            __syncthreads();

            // stage pooled row (agent-scope loads: bypass possibly-stale L2)
            p_lds[t] = __hip_atomic_load(&pooled[b * CH + t], __ATOMIC_RELAXED,
                                         __HIP_MEMORY_SCOPE_AGENT);
            __syncthreads();

            // fc1 + leaky relu
            {
                const int r   = t >> 4;
                const int seg = t & 15;
                const float* wrow = w1 + r * CH + seg * 16;
                const float* pp   = p_lds + seg * 16;
                float ps = 0.0f;
#pragma unroll
                for (int j = 0; j < 16; ++j)
                    ps += pp[j] * wrow[j];
#pragma unroll
                for (int m = 8; m > 0; m >>= 1)
                    ps += __shfl_xor(ps, m, 64);
                if (seg == 0) {
                    float h = ps + b1[r];
                    h_lds[r] = (h >= 0.0f) ? h : 0.01f * h;
                }
            }
            __syncthreads();

            // fc2 + sigmoid for this block's single channel
            if (t == 0) {
                float z = b2[c];
                const float* wcol = w2 + c * CRR;
#pragma unroll
                for (int r = 0; r < CRR; ++r)
                    z += h_lds[r] * wcol[r];
                s_gate = 1.0f / (1.0f + expf(-z));
            }
            __syncthreads();
            const float sc = s_gate;

            const vfloat4* xin = reinterpret_cast<const vfloat4*>(x + (size_t)plane * HWSZ);
            vfloat4*       o   = reinterpret_cast<vfloat4*>(out + (size_t)plane * HWSZ);
#pragma unroll
            for (int k = 0; k < 16; ++k) {
                vfloat4 v = xin[k * 256 + t];
                v *= sc;
                __builtin_nontemporal_store(v, &o[k * 256 + t]);
            }
            __syncthreads();   // p_lds/h_lds reuse next iteration
        }

        if (i < ITER) prev_plane = i * NBLK + p;
    }
}

extern "C" void kernel_launch(void* const* d_in, const int* in_sizes, int n_in,
                              void* d_out, int out_size, void* d_ws, size_t ws_size,
                              hipStream_t stream) {
    const float* x  = (const float*)d_in[0];   // [16,256,128,128]
    const float* w1 = (const float*)d_in[1];   // [16,256]
    const float* b1 = (const float*)d_in[2];   // [16]
    const float* w2 = (const float*)d_in[3];   // [256,16]
    const float* b2 = (const float*)d_in[4];   // [256]
    float* out    = (float*)d_out;

    float*        pooled = (float*)d_ws;                 // NPLANES floats
    unsigned int* cnt    = (unsigned int*)(pooled + NPLANES);  // BATCH uints

    init_kernel<<<1, 64, 0, stream>>>(cnt);
    se_persistent<<<NBLK, 256, 0, stream>>>(x, w1, b1, w2, b2, out, pooled, cnt);
}